// Round 15
// baseline (666.788 us; speedup 1.0000x reference)
//
#include <hip/hip_runtime.h>
#include <hip/hip_bf16.h>

// ---------------------------------------------------------------------------
// GraphSAGE distance estimator.
//   CSR build (both graphs batched): LDS bucket hist -> scan -> bucket-grouped
//   scatter of PACKED (src | dlocal<<17) ints -> per-bucket LDS counting sort
//   with LDS staging (contiguous flush) + parallel block scan.
//   Per layer: {Y,R} = x@{Wl,Wr} fused GEMM, W+x both in LDS (broadcast
//   ds_reads), W packed float4, explicit fmaf chains. ROWS=128/block
//   (16 rows/wave): halves W-stage + W-read cost per FMA vs R14's 8 rows.
//   Y stored BF16 (one cache line per agg gather row); agg unrolled 32-deep.
//   H = relu(csr-mean(Y) + bl + R) fused into aggregate.
//   Pool: 8 partial blocks -> final_mlp (block/graph, thread j owns feature j).
// ---------------------------------------------------------------------------

#define NB    128    // dst buckets (pow2)
#define EPB   16384  // edges per grouping block
#define BWMAX 1024   // max nodes per bucket (LDS arrays in sort)
#define PP    8      // pool partials per graph
#define SRCB  17     // bits for src id in packed pair (N <= 131072)
#define SCAP  28672  // staged edges per bucket (112 KB LDS)

// ---- CSR build (batched over both graphs) ----------------------------------

__global__ __launch_bounds__(256) void p1_hist(const int* __restrict__ dstS,
                                               const int* __restrict__ dstG,
                                               int* __restrict__ blkhist,
                                               int E, int bsh, int nblk) {
    const int g = blockIdx.x / nblk;
    const int blk = blockIdx.x % nblk;
    const int* __restrict__ dst = g ? dstG : dstS;
    __shared__ int h[NB];
    for (int i = threadIdx.x; i < NB; i += 256) h[i] = 0;
    __syncthreads();
    const int base = blk * EPB;
    for (int k = 0; k < EPB; k += 256) {
        const int e = base + k + threadIdx.x;
        if (e < E) atomicAdd(&h[dst[e] >> bsh], 1);
    }
    __syncthreads();
    for (int i = threadIdx.x; i < NB; i += 256)
        blkhist[((size_t)(g * nblk + blk)) * NB + i] = h[i];
}

__global__ __launch_bounds__(NB) void p1_scan(const int* __restrict__ blkhist,
                                              int* __restrict__ basem,
                                              int* __restrict__ bucket_base,
                                              int nblk) {
    __shared__ int lds[NB];
    const int g = blockIdx.x;
    const int* __restrict__ bh = blkhist + (size_t)g * nblk * NB;
    int* __restrict__ bm = basem + (size_t)g * nblk * NB;
    int* __restrict__ bb = bucket_base + (size_t)g * (NB + 1);
    const int b = threadIdx.x;
    int s = 0;
    int k = 0;
    for (; k + 8 <= nblk; k += 8) {
        int v[8];
        #pragma unroll
        for (int t = 0; t < 8; ++t) v[t] = bh[(size_t)(k + t) * NB + b];
        #pragma unroll
        for (int t = 0; t < 8; ++t) s += v[t];
    }
    for (; k < nblk; ++k) s += bh[(size_t)k * NB + b];
    lds[b] = s;
    __syncthreads();
    for (int off = 1; off < NB; off <<= 1) {
        int v = (b >= off) ? lds[b - off] : 0;
        __syncthreads();
        lds[b] += v;
        __syncthreads();
    }
    int run = lds[b] - s;  // exclusive prefix
    bb[b] = run;
    if (b == NB - 1) bb[NB] = run + s;
    k = 0;
    for (; k + 8 <= nblk; k += 8) {
        int c[8];
        #pragma unroll
        for (int t = 0; t < 8; ++t) c[t] = bh[(size_t)(k + t) * NB + b];
        #pragma unroll
        for (int t = 0; t < 8; ++t) {
            bm[(size_t)(k + t) * NB + b] = run;
            run += c[t];
        }
    }
    for (; k < nblk; ++k) {
        const int c = bh[(size_t)k * NB + b];
        bm[(size_t)k * NB + b] = run;
        run += c;
    }
}

__global__ __launch_bounds__(256) void p1_scatter(const int* __restrict__ eiS,
                                                  const int* __restrict__ eiG,
                                                  const int* __restrict__ basem,
                                                  int* __restrict__ pairs,
                                                  int E, int bsh, int nblk) {
    const int g = blockIdx.x / nblk;
    const int blk = blockIdx.x % nblk;
    const int* __restrict__ src = g ? eiG : eiS;
    const int* __restrict__ dst = src + E;
    int* __restrict__ pr = pairs + (size_t)g * E;
    const int bwm = (1 << bsh) - 1;
    __shared__ int cur[NB];
    for (int i = threadIdx.x; i < NB; i += 256)
        cur[i] = basem[((size_t)(g * nblk + blk)) * NB + i];
    __syncthreads();
    const int base = blk * EPB;
    for (int k = 0; k < EPB; k += 256) {
        const int e = base + k + threadIdx.x;
        if (e < E) {
            const int d = dst[e];
            const int s = src[e];
            const int p = atomicAdd(&cur[d >> bsh], 1);
            pr[p] = s | ((d & bwm) << SRCB);   // packed: src(17b) | dlocal(<=10b)
        }
    }
}

// Per-bucket counting sort with LDS staging + parallel block scan.
__global__ __launch_bounds__(512) void p2_sort(const int* __restrict__ pairs,
                                               const int* __restrict__ bucket_base,
                                               int* __restrict__ csr,
                                               int* __restrict__ row_start,
                                               int N, int E, int bsh) {
    __shared__ int stage[SCAP];   // 112 KB
    __shared__ int cnt[BWMAX];    // 4 KB
    __shared__ int off[BWMAX];    // 4 KB
    __shared__ int ws[512];       // 2 KB
    const int g = blockIdx.x / NB;
    const int b = blockIdx.x % NB;
    const int bw = 1 << bsh;
    const int lo = b * bw;
    int nn = N - lo;
    if (nn <= 0) return;
    if (nn > bw) nn = bw;
    const int* __restrict__ pr = pairs + (size_t)g * E;
    const int* __restrict__ bb = bucket_base + (size_t)g * (NB + 1);
    int* __restrict__ cs = csr + (size_t)g * E;
    int* __restrict__ rs = row_start + (size_t)g * (N + 1);
    const int tid = threadIdx.x;
    for (int i = tid; i < nn; i += 512) cnt[i] = 0;
    __syncthreads();
    const int e0 = bb[b];
    const int e1 = bb[b + 1];
    const int ne = e1 - e0;
    for (int e = e0 + tid; e < e1; e += 512)
        atomicAdd(&cnt[pr[e] >> SRCB], 1);
    __syncthreads();
    {
        const int i0 = 2 * tid, i1 = 2 * tid + 1;
        const int c0 = (i0 < nn) ? cnt[i0] : 0;
        const int c1 = (i1 < nn) ? cnt[i1] : 0;
        const int s = c0 + c1;
        ws[tid] = s;
        __syncthreads();
        for (int o = 1; o < 512; o <<= 1) {
            int v = (tid >= o) ? ws[tid - o] : 0;
            __syncthreads();
            ws[tid] += v;
            __syncthreads();
        }
        const int base = e0 + ws[tid] - s;  // exclusive
        if (i0 < nn) off[i0] = base;
        if (i1 < nn) off[i1] = base + c0;
    }
    __syncthreads();
    for (int i = tid; i < nn; i += 512) {
        rs[lo + i] = off[i];
        cnt[i] = off[i];  // reuse as cursor
    }
    if (lo + nn == N && tid == 0) rs[N] = e1;
    __syncthreads();
    if (ne <= SCAP) {
        for (int e = e0 + tid; e < e1; e += 512) {
            const int v = pr[e];
            const int pos = atomicAdd(&cnt[v >> SRCB], 1);
            stage[pos - e0] = v & ((1 << SRCB) - 1);
        }
        __syncthreads();
        for (int i = tid; i < ne; i += 512) cs[e0 + i] = stage[i];
    } else {
        for (int e = e0 + tid; e < e1; e += 512) {
            const int v = pr[e];
            const int pos = atomicAdd(&cnt[v >> SRCB], 1);
            cs[pos] = v & ((1 << SRCB) - 1);
        }
    }
}

// ---- fused dual-weight GEMM: Y(bf16) = x@Wl, R(fp32) = x@Wr -----------------
// 512 thr = 8 waves x 16 rows = 128 rows/block. KC=64 K-chunks. W packed
// (wl_k,wr_k,wl_k+1,wr_k+1) float4 in LDS (32KB); x tile (32KB) staged
// coalesced then consumed via broadcast ds_reads. 16 rows/wave doubles the
// FMA:(W-read + stage) ratio vs 8 rows (R14: FMA-productive ~48% of VALU).
template <int K>
__global__ __launch_bounds__(512) void gemm_fused(const float* __restrict__ x,
                                                  const float* __restrict__ Wl,
                                                  const float* __restrict__ Wr,
                                                  __hip_bfloat16* __restrict__ Y,
                                                  float* __restrict__ R, int n) {
    constexpr int KC = 64;
    constexpr int ROWS = 128;
    __shared__ float4 ldsW[(KC / 2) * 64]; // 32 KB
    __shared__ float  ldsX[ROWS * KC];     // 32 KB
    const int tid = threadIdx.x;
    const int lane = tid & 63;
    const int wid = tid >> 6;
    const int rbase = blockIdx.x * ROWS;

    float accY[16], accR[16];
    #pragma unroll
    for (int r = 0; r < 16; ++r) { accY[r] = 0.f; accR[r] = 0.f; }

    for (int k0 = 0; k0 < K; k0 += KC) {
        __syncthreads();
        for (int i = tid; i < (KC / 2) * 64; i += 512) {
            const int k2 = i >> 6;
            const int col = i & 63;
            const int ka = k0 + k2 * 2;
            ldsW[i] = make_float4(Wl[(size_t)ka * 64 + col], Wr[(size_t)ka * 64 + col],
                                  Wl[(size_t)(ka + 1) * 64 + col], Wr[(size_t)(ka + 1) * 64 + col]);
        }
        {
            constexpr int F4R = KC / 4;           // float4 per row = 16
            float4* lx = (float4*)ldsX;
            for (int i = tid; i < ROWS * F4R; i += 512) {
                const int rr = i / F4R;
                const int cc = i % F4R;
                int row = rbase + rr;
                if (row > n - 1) row = n - 1;
                lx[i] = *(const float4*)(x + (size_t)row * K + k0 + cc * 4);
            }
        }
        __syncthreads();
        const int rw = wid * 16;
        for (int k4 = 0; k4 < KC / 4; ++k4) {
            const float4 wA = ldsW[(k4 * 2 + 0) * 64 + lane]; // k, k+1
            const float4 wB = ldsW[(k4 * 2 + 1) * 64 + lane]; // k+2, k+3
            #pragma unroll
            for (int r = 0; r < 16; ++r) {
                const float4 xv = *(const float4*)(&ldsX[(rw + r) * KC + k4 * 4]);
                float y = accY[r];
                float z = accR[r];
                y = fmaf(xv.x, wA.x, y);
                z = fmaf(xv.x, wA.y, z);
                y = fmaf(xv.y, wA.z, y);
                z = fmaf(xv.y, wA.w, z);
                y = fmaf(xv.z, wB.x, y);
                z = fmaf(xv.z, wB.y, z);
                y = fmaf(xv.w, wB.z, y);
                z = fmaf(xv.w, wB.w, z);
                accY[r] = y;
                accR[r] = z;
            }
        }
    }
    #pragma unroll
    for (int r = 0; r < 16; ++r) {
        const int row = rbase + wid * 16 + r;
        if (row < n) {
            Y[(size_t)row * 64 + lane] = __float2bfloat16(accY[r]);
            R[(size_t)row * 64 + lane] = accR[r];
        }
    }
}

// ---- aggregate + epilogue: H = relu(mean_csr(Y) + bl + R) -------------------
__global__ __launch_bounds__(256) void agg_fused(const __hip_bfloat16* __restrict__ Y,
                                                 const float* __restrict__ R,
                                                 const float* __restrict__ bl,
                                                 const int* __restrict__ csr,
                                                 const int* __restrict__ row_start,
                                                 float* __restrict__ H, int n) {
    const int wid = threadIdx.x >> 6;
    const int lane = threadIdx.x & 63;
    const int i = blockIdx.x * 4 + wid;
    if (i >= n) return;
    const int r0 = __builtin_amdgcn_readfirstlane(row_start[i]);
    const int r1 = __builtin_amdgcn_readfirstlane(row_start[i + 1]);
    float a[32];
    #pragma unroll
    for (int t = 0; t < 32; ++t) a[t] = 0.f;
    int e = r0;
    for (; e + 32 <= r1; e += 32) {
        #pragma unroll
        for (int t = 0; t < 32; ++t)
            a[t] += __bfloat162float(Y[(size_t)csr[e + t] * 64 + lane]);
    }
    for (; e + 8 <= r1; e += 8) {
        #pragma unroll
        for (int t = 0; t < 8; ++t)
            a[t] += __bfloat162float(Y[(size_t)csr[e + t] * 64 + lane]);
    }
    for (; e < r1; ++e) a[0] += __bfloat162float(Y[(size_t)csr[e] * 64 + lane]);
    float acc = 0.f;
    #pragma unroll
    for (int t = 0; t < 32; ++t) acc += a[t];
    const int c = r1 - r0;
    const float sc = (c > 0) ? (1.0f / (float)c) : 1.0f;
    const float v = acc * sc + bl[lane] + R[(size_t)i * 64 + lane];
    H[(size_t)i * 64 + lane] = fmaxf(v, 0.0f);
}

// ---- pooling: PP partial blocks per graph (sorted batch, binary search) -----
__global__ __launch_bounds__(256) void pool_part(const float* __restrict__ H,
                                                 const int* __restrict__ batch,
                                                 float* __restrict__ parts,
                                                 int* __restrict__ pcnt, int n) {
    const int b = blockIdx.x / PP;
    const int p = blockIdx.x % PP;
    int lo = 0, hi = n;
    while (lo < hi) { int m = (lo + hi) >> 1; if (batch[m] < b) lo = m + 1; else hi = m; }
    const int beg = lo;
    hi = n;
    while (lo < hi) { int m = (lo + hi) >> 1; if (batch[m] < b + 1) lo = m + 1; else hi = m; }
    const int end = lo;
    const int len = end - beg;
    const int chunk = (len + PP - 1) / PP;
    const int s0 = beg + p * chunk;
    int s1 = s0 + chunk; if (s1 > end) s1 = end;

    const int wid = threadIdx.x >> 6;
    const int lane = threadIdx.x & 63;
    float acc = 0.f;
    for (int i = s0 + wid; i < s1; i += 4)
        acc += H[(size_t)i * 64 + lane];
    __shared__ float part[4][64];
    part[wid][lane] = acc;
    __syncthreads();
    if (wid == 0) {
        const float s = (part[0][lane] + part[1][lane]) + (part[2][lane] + part[3][lane]);
        parts[(size_t)(b * PP + p) * 64 + lane] = s;
        if (lane == 0 && p == 0) pcnt[b] = len;
    }
}

// ---- final MLP: one block per graph, thread j owns output feature j ---------
__global__ __launch_bounds__(64) void final_mlp(const float* __restrict__ partsS,
                                                const int* __restrict__ cntS,
                                                const float* __restrict__ partsG,
                                                const int* __restrict__ cntG,
                                                const float* __restrict__ depth,
                                                const float* __restrict__ W1,
                                                const float* __restrict__ b1,
                                                const float* __restrict__ W2,
                                                const float* __restrict__ b2,
                                                float* __restrict__ out, int Bn) {
    const int b = blockIdx.x;
    const int j = threadIdx.x;  // 0..63
    float dsum = 0.f;
    for (int i = j; i < Bn; i += 64) dsum += depth[i];
    #pragma unroll
    for (int o = 32; o > 0; o >>= 1) dsum += __shfl_xor(dsum, o);
    const float mean = dsum / (float)Bn;
    float dvar = 0.f;
    for (int i = j; i < Bn; i += 64) { const float t = depth[i] - mean; dvar = fmaf(t, t, dvar); }
    #pragma unroll
    for (int o = 32; o > 0; o >>= 1) dvar += __shfl_xor(dvar, o);
    const float stdv = sqrtf(dvar / (float)Bn);
    const float dn = (depth[b] - mean) / (stdv + 1e-6f);

    __shared__ float f[129];
    {
        float s = 0.f, g = 0.f;
        #pragma unroll
        for (int p = 0; p < PP; ++p) {
            s += partsS[(size_t)(b * PP + p) * 64 + j];
            g += partsG[(size_t)(b * PP + p) * 64 + j];
        }
        int cs = cntS[b]; if (cs < 1) cs = 1;
        int cg = cntG[b]; if (cg < 1) cg = 1;
        f[j] = s / (float)cs;
        f[64 + j] = g / (float)cg;
        if (j == 0) f[128] = dn;
    }
    __syncthreads();
    float acc = b1[j];
    #pragma unroll 8
    for (int k = 0; k < 129; ++k)
        acc = fmaf(f[k], W1[(size_t)k * 64 + j], acc);
    float o = fmaxf(acc, 0.0f) * W2[j];
    #pragma unroll
    for (int of = 32; of > 0; of >>= 1) o += __shfl_xor(o, of);
    if (j == 0) out[b] = o + b2[0];
}

extern "C" void kernel_launch(void* const* d_in, const int* in_sizes, int n_in,
                              void* d_out, int out_size, void* d_ws, size_t ws_size,
                              hipStream_t stream) {
    const float* state_x     = (const float*)d_in[0];
    const int*   state_ei    = (const int*)d_in[1];
    const int*   state_batch = (const int*)d_in[2];
    const float* goal_x      = (const float*)d_in[3];
    const int*   goal_ei     = (const int*)d_in[4];
    const int*   goal_batch  = (const int*)d_in[5];
    const float* depth       = (const float*)d_in[6];
    const float* s1_Wl = (const float*)d_in[7];
    const float* s1_bl = (const float*)d_in[8];
    const float* s1_Wr = (const float*)d_in[9];
    const float* s2_Wl = (const float*)d_in[10];
    const float* s2_bl = (const float*)d_in[11];
    const float* s2_Wr = (const float*)d_in[12];
    const float* g1_Wl = (const float*)d_in[13];
    const float* g1_bl = (const float*)d_in[14];
    const float* g1_Wr = (const float*)d_in[15];
    const float* g2_Wl = (const float*)d_in[16];
    const float* g2_bl = (const float*)d_in[17];
    const float* g2_Wr = (const float*)d_in[18];
    const float* mlp_W1 = (const float*)d_in[19];
    const float* mlp_b1 = (const float*)d_in[20];
    const float* mlp_W2 = (const float*)d_in[21];
    const float* mlp_b2 = (const float*)d_in[22];

    const int N  = in_sizes[0] / 128;
    const int E  = in_sizes[1] / 2;
    const int Bn = in_sizes[6];
    const int nblk = (E + EPB - 1) / EPB;
    int bsh = 0;
    while (((size_t)NB << bsh) < (size_t)N) ++bsh;  // bucket width 2^bsh

    char* w = (char*)d_ws;
    auto alloc = [&](size_t bytes) {
        char* p = w;
        w += (bytes + 255) & ~(size_t)255;
        return p;
    };
    char*  bufYraw     = alloc((size_t)N * 64 * sizeof(float));  // bf16 Y + pairs alias
    float* bufR        = (float*)alloc((size_t)N * 64 * sizeof(float));
    float* bufH        = (float*)alloc((size_t)N * 64 * sizeof(float));
    int*   csr         = (int*)alloc((size_t)2 * E * sizeof(int));
    int*   row_start   = (int*)alloc((size_t)2 * (N + 1) * sizeof(int));
    int*   blkhist     = (int*)alloc((size_t)2 * nblk * NB * sizeof(int));
    int*   basem       = (int*)alloc((size_t)2 * nblk * NB * sizeof(int));
    int*   bucket_base = (int*)alloc((size_t)2 * (NB + 1) * sizeof(int));
    float* partsS      = (float*)alloc((size_t)Bn * PP * 64 * sizeof(float));
    float* partsG      = (float*)alloc((size_t)Bn * PP * 64 * sizeof(float));
    int*   cntS        = (int*)alloc((size_t)Bn * sizeof(int));
    int*   cntG        = (int*)alloc((size_t)Bn * sizeof(int));
    __hip_bfloat16* bufY = (__hip_bfloat16*)bufYraw;
    int*   pairs       = (int*)bufYraw;  // packed pairs alias bufY (dead in CSR build)
    const size_t need = (size_t)(w - (char*)d_ws);
    const bool pairs_fit = (size_t)2 * E * sizeof(int) <= (size_t)N * 64 * sizeof(float);
    if (need > ws_size || (1 << bsh) > BWMAX || !pairs_fit || N > (1 << SRCB)) {
        hipMemsetAsync(d_out, 0, (size_t)out_size * sizeof(float), stream);
        return;
    }

    // ---- CSR build, both graphs ----
    p1_hist<<<2 * nblk, 256, 0, stream>>>(state_ei + E, goal_ei + E, blkhist, E, bsh, nblk);
    p1_scan<<<2, NB, 0, stream>>>(blkhist, basem, bucket_base, nblk);
    p1_scatter<<<2 * nblk, 256, 0, stream>>>(state_ei, goal_ei, basem, pairs, E, bsh, nblk);
    p2_sort<<<2 * NB, 512, 0, stream>>>(pairs, bucket_base, csr, row_start, N, E, bsh);

    const int g128 = (N + 127) / 128;
    const int g4   = (N + 3) / 4;
    const int* csrS = csr;
    const int* csrG = csr + E;
    const int* rsS  = row_start;
    const int* rsG  = row_start + (N + 1);

    // ---- state encoder ----
    gemm_fused<128><<<g128, 512, 0, stream>>>(state_x, s1_Wl, s1_Wr, bufY, bufR, N);
    agg_fused<<<g4, 256, 0, stream>>>(bufY, bufR, s1_bl, csrS, rsS, bufH, N);
    gemm_fused<64><<<g128, 512, 0, stream>>>(bufH, s2_Wl, s2_Wr, bufY, bufR, N);
    agg_fused<<<g4, 256, 0, stream>>>(bufY, bufR, s2_bl, csrS, rsS, bufH, N);
    pool_part<<<Bn * PP, 256, 0, stream>>>(bufH, state_batch, partsS, cntS, N);

    // ---- goal encoder ----
    gemm_fused<128><<<g128, 512, 0, stream>>>(goal_x, g1_Wl, g1_Wr, bufY, bufR, N);
    agg_fused<<<g4, 256, 0, stream>>>(bufY, bufR, g1_bl, csrG, rsG, bufH, N);
    gemm_fused<64><<<g128, 512, 0, stream>>>(bufH, g2_Wl, g2_Wr, bufY, bufR, N);
    agg_fused<<<g4, 256, 0, stream>>>(bufY, bufR, g2_bl, csrG, rsG, bufH, N);
    pool_part<<<Bn * PP, 256, 0, stream>>>(bufH, goal_batch, partsG, cntG, N);

    final_mlp<<<Bn, 64, 0, stream>>>(partsS, cntS, partsG, cntG, depth,
                                     mlp_W1, mlp_b1, mlp_W2, mlp_b2, (float*)d_out, Bn);
}

// Round 16
// 640.530 us; speedup vs baseline: 1.0410x; 1.0410x over previous
//
#include <hip/hip_runtime.h>
#include <hip/hip_bf16.h>

// ---------------------------------------------------------------------------
// GraphSAGE distance estimator.
//   CSR build (both graphs batched): LDS bucket hist -> scan -> bucket-grouped
//   scatter of PACKED (src | dlocal<<17) ints -> per-bucket LDS counting sort
//   with LDS staging (contiguous flush) + parallel block scan.
//   Per layer: {Y,R} = x@{Wl,Wr} fused GEMM, W+x both in LDS (broadcast
//   ds_reads), W packed float4, explicit fmaf chains. ROWS=64/block:
//   1563 blocks at 3 blocks/CU divides the machine evenly (R15: ROWS=128's
//   782-block grid at 2/CU ran round 2 half-empty, -13%).
//   Y AND R stored BF16 (agg gather row = one line; R is additive pre-ReLU,
//   error averages out in pooling); fp32 accumulation everywhere.
//   H = relu(csr-mean(Y) + bl + R) fused into aggregate.
//   Pool: 8 partial blocks -> final_mlp (block/graph, thread j owns feature j).
// ---------------------------------------------------------------------------

#define NB    128    // dst buckets (pow2)
#define EPB   16384  // edges per grouping block
#define BWMAX 1024   // max nodes per bucket (LDS arrays in sort)
#define PP    8      // pool partials per graph
#define SRCB  17     // bits for src id in packed pair (N <= 131072)
#define SCAP  28672  // staged edges per bucket (112 KB LDS)

// ---- CSR build (batched over both graphs) ----------------------------------

__global__ __launch_bounds__(256) void p1_hist(const int* __restrict__ dstS,
                                               const int* __restrict__ dstG,
                                               int* __restrict__ blkhist,
                                               int E, int bsh, int nblk) {
    const int g = blockIdx.x / nblk;
    const int blk = blockIdx.x % nblk;
    const int* __restrict__ dst = g ? dstG : dstS;
    __shared__ int h[NB];
    for (int i = threadIdx.x; i < NB; i += 256) h[i] = 0;
    __syncthreads();
    const int base = blk * EPB;
    for (int k = 0; k < EPB; k += 256) {
        const int e = base + k + threadIdx.x;
        if (e < E) atomicAdd(&h[dst[e] >> bsh], 1);
    }
    __syncthreads();
    for (int i = threadIdx.x; i < NB; i += 256)
        blkhist[((size_t)(g * nblk + blk)) * NB + i] = h[i];
}

__global__ __launch_bounds__(NB) void p1_scan(const int* __restrict__ blkhist,
                                              int* __restrict__ basem,
                                              int* __restrict__ bucket_base,
                                              int nblk) {
    __shared__ int lds[NB];
    const int g = blockIdx.x;
    const int* __restrict__ bh = blkhist + (size_t)g * nblk * NB;
    int* __restrict__ bm = basem + (size_t)g * nblk * NB;
    int* __restrict__ bb = bucket_base + (size_t)g * (NB + 1);
    const int b = threadIdx.x;
    int s = 0;
    int k = 0;
    for (; k + 8 <= nblk; k += 8) {
        int v[8];
        #pragma unroll
        for (int t = 0; t < 8; ++t) v[t] = bh[(size_t)(k + t) * NB + b];
        #pragma unroll
        for (int t = 0; t < 8; ++t) s += v[t];
    }
    for (; k < nblk; ++k) s += bh[(size_t)k * NB + b];
    lds[b] = s;
    __syncthreads();
    for (int off = 1; off < NB; off <<= 1) {
        int v = (b >= off) ? lds[b - off] : 0;
        __syncthreads();
        lds[b] += v;
        __syncthreads();
    }
    int run = lds[b] - s;  // exclusive prefix
    bb[b] = run;
    if (b == NB - 1) bb[NB] = run + s;
    k = 0;
    for (; k + 8 <= nblk; k += 8) {
        int c[8];
        #pragma unroll
        for (int t = 0; t < 8; ++t) c[t] = bh[(size_t)(k + t) * NB + b];
        #pragma unroll
        for (int t = 0; t < 8; ++t) {
            bm[(size_t)(k + t) * NB + b] = run;
            run += c[t];
        }
    }
    for (; k < nblk; ++k) {
        const int c = bh[(size_t)k * NB + b];
        bm[(size_t)k * NB + b] = run;
        run += c;
    }
}

__global__ __launch_bounds__(256) void p1_scatter(const int* __restrict__ eiS,
                                                  const int* __restrict__ eiG,
                                                  const int* __restrict__ basem,
                                                  int* __restrict__ pairs,
                                                  int E, int bsh, int nblk) {
    const int g = blockIdx.x / nblk;
    const int blk = blockIdx.x % nblk;
    const int* __restrict__ src = g ? eiG : eiS;
    const int* __restrict__ dst = src + E;
    int* __restrict__ pr = pairs + (size_t)g * E;
    const int bwm = (1 << bsh) - 1;
    __shared__ int cur[NB];
    for (int i = threadIdx.x; i < NB; i += 256)
        cur[i] = basem[((size_t)(g * nblk + blk)) * NB + i];
    __syncthreads();
    const int base = blk * EPB;
    for (int k = 0; k < EPB; k += 256) {
        const int e = base + k + threadIdx.x;
        if (e < E) {
            const int d = dst[e];
            const int s = src[e];
            const int p = atomicAdd(&cur[d >> bsh], 1);
            pr[p] = s | ((d & bwm) << SRCB);   // packed: src(17b) | dlocal(<=10b)
        }
    }
}

// Per-bucket counting sort with LDS staging + parallel block scan.
__global__ __launch_bounds__(512) void p2_sort(const int* __restrict__ pairs,
                                               const int* __restrict__ bucket_base,
                                               int* __restrict__ csr,
                                               int* __restrict__ row_start,
                                               int N, int E, int bsh) {
    __shared__ int stage[SCAP];   // 112 KB
    __shared__ int cnt[BWMAX];    // 4 KB
    __shared__ int off[BWMAX];    // 4 KB
    __shared__ int ws[512];       // 2 KB
    const int g = blockIdx.x / NB;
    const int b = blockIdx.x % NB;
    const int bw = 1 << bsh;
    const int lo = b * bw;
    int nn = N - lo;
    if (nn <= 0) return;
    if (nn > bw) nn = bw;
    const int* __restrict__ pr = pairs + (size_t)g * E;
    const int* __restrict__ bb = bucket_base + (size_t)g * (NB + 1);
    int* __restrict__ cs = csr + (size_t)g * E;
    int* __restrict__ rs = row_start + (size_t)g * (N + 1);
    const int tid = threadIdx.x;
    for (int i = tid; i < nn; i += 512) cnt[i] = 0;
    __syncthreads();
    const int e0 = bb[b];
    const int e1 = bb[b + 1];
    const int ne = e1 - e0;
    for (int e = e0 + tid; e < e1; e += 512)
        atomicAdd(&cnt[pr[e] >> SRCB], 1);
    __syncthreads();
    {
        const int i0 = 2 * tid, i1 = 2 * tid + 1;
        const int c0 = (i0 < nn) ? cnt[i0] : 0;
        const int c1 = (i1 < nn) ? cnt[i1] : 0;
        const int s = c0 + c1;
        ws[tid] = s;
        __syncthreads();
        for (int o = 1; o < 512; o <<= 1) {
            int v = (tid >= o) ? ws[tid - o] : 0;
            __syncthreads();
            ws[tid] += v;
            __syncthreads();
        }
        const int base = e0 + ws[tid] - s;  // exclusive
        if (i0 < nn) off[i0] = base;
        if (i1 < nn) off[i1] = base + c0;
    }
    __syncthreads();
    for (int i = tid; i < nn; i += 512) {
        rs[lo + i] = off[i];
        cnt[i] = off[i];  // reuse as cursor
    }
    if (lo + nn == N && tid == 0) rs[N] = e1;
    __syncthreads();
    if (ne <= SCAP) {
        for (int e = e0 + tid; e < e1; e += 512) {
            const int v = pr[e];
            const int pos = atomicAdd(&cnt[v >> SRCB], 1);
            stage[pos - e0] = v & ((1 << SRCB) - 1);
        }
        __syncthreads();
        for (int i = tid; i < ne; i += 512) cs[e0 + i] = stage[i];
    } else {
        for (int e = e0 + tid; e < e1; e += 512) {
            const int v = pr[e];
            const int pos = atomicAdd(&cnt[v >> SRCB], 1);
            cs[pos] = v & ((1 << SRCB) - 1);
        }
    }
}

// ---- fused dual-weight GEMM: Y(bf16) = x@Wl, R(bf16) = x@Wr -----------------
// R14-exact structure: 512 thr = 8 waves x 8 rows = 64 rows/block, KC=64,
// 48KB LDS -> 3 blocks/CU; 1563-block grid divides evenly (R15 lesson).
template <int K>
__global__ __launch_bounds__(512) void gemm_fused(const float* __restrict__ x,
                                                  const float* __restrict__ Wl,
                                                  const float* __restrict__ Wr,
                                                  __hip_bfloat16* __restrict__ Y,
                                                  __hip_bfloat16* __restrict__ R, int n) {
    constexpr int KC = 64;
    constexpr int ROWS = 64;
    __shared__ float4 ldsW[(KC / 2) * 64]; // 32 KB, (wl_2k,wr_2k,wl_2k+1,wr_2k+1)
    __shared__ float  ldsX[ROWS * KC];     // 16 KB
    const int tid = threadIdx.x;
    const int lane = tid & 63;
    const int wid = tid >> 6;
    const int rbase = blockIdx.x * ROWS;

    float accY[8], accR[8];
    #pragma unroll
    for (int r = 0; r < 8; ++r) { accY[r] = 0.f; accR[r] = 0.f; }

    for (int k0 = 0; k0 < K; k0 += KC) {
        __syncthreads();
        for (int i = tid; i < (KC / 2) * 64; i += 512) {
            const int k2 = i >> 6;
            const int col = i & 63;
            const int ka = k0 + k2 * 2;
            ldsW[i] = make_float4(Wl[(size_t)ka * 64 + col], Wr[(size_t)ka * 64 + col],
                                  Wl[(size_t)(ka + 1) * 64 + col], Wr[(size_t)(ka + 1) * 64 + col]);
        }
        {
            constexpr int F4R = KC / 4;           // float4 per row = 16
            float4* lx = (float4*)ldsX;
            for (int i = tid; i < ROWS * F4R; i += 512) {
                const int rr = i / F4R;
                const int cc = i % F4R;
                int row = rbase + rr;
                if (row > n - 1) row = n - 1;
                lx[i] = *(const float4*)(x + (size_t)row * K + k0 + cc * 4);
            }
        }
        __syncthreads();
        const int rw = wid * 8;
        #pragma unroll 2
        for (int k4 = 0; k4 < KC / 4; ++k4) {
            const float4 wA = ldsW[(k4 * 2 + 0) * 64 + lane]; // k, k+1
            const float4 wB = ldsW[(k4 * 2 + 1) * 64 + lane]; // k+2, k+3
            #pragma unroll
            for (int r = 0; r < 8; ++r) {
                const float4 xv = *(const float4*)(&ldsX[(rw + r) * KC + k4 * 4]);
                float y = accY[r];
                float z = accR[r];
                y = fmaf(xv.x, wA.x, y);
                z = fmaf(xv.x, wA.y, z);
                y = fmaf(xv.y, wA.z, y);
                z = fmaf(xv.y, wA.w, z);
                y = fmaf(xv.z, wB.x, y);
                z = fmaf(xv.z, wB.y, z);
                y = fmaf(xv.w, wB.z, y);
                z = fmaf(xv.w, wB.w, z);
                accY[r] = y;
                accR[r] = z;
            }
        }
    }
    #pragma unroll
    for (int r = 0; r < 8; ++r) {
        const int row = rbase + wid * 8 + r;
        if (row < n) {
            Y[(size_t)row * 64 + lane] = __float2bfloat16(accY[r]);
            R[(size_t)row * 64 + lane] = __float2bfloat16(accR[r]);
        }
    }
}

// ---- aggregate + epilogue: H = relu(mean_csr(Y) + bl + R) -------------------
// Y, R both bf16 (one cache line per row); fp32 accumulation.
__global__ __launch_bounds__(256) void agg_fused(const __hip_bfloat16* __restrict__ Y,
                                                 const __hip_bfloat16* __restrict__ R,
                                                 const float* __restrict__ bl,
                                                 const int* __restrict__ csr,
                                                 const int* __restrict__ row_start,
                                                 float* __restrict__ H, int n) {
    const int wid = threadIdx.x >> 6;
    const int lane = threadIdx.x & 63;
    const int i = blockIdx.x * 4 + wid;
    if (i >= n) return;
    const int r0 = __builtin_amdgcn_readfirstlane(row_start[i]);
    const int r1 = __builtin_amdgcn_readfirstlane(row_start[i + 1]);
    float a[32];
    #pragma unroll
    for (int t = 0; t < 32; ++t) a[t] = 0.f;
    int e = r0;
    for (; e + 32 <= r1; e += 32) {
        #pragma unroll
        for (int t = 0; t < 32; ++t)
            a[t] += __bfloat162float(Y[(size_t)csr[e + t] * 64 + lane]);
    }
    for (; e + 8 <= r1; e += 8) {
        #pragma unroll
        for (int t = 0; t < 8; ++t)
            a[t] += __bfloat162float(Y[(size_t)csr[e + t] * 64 + lane]);
    }
    for (; e < r1; ++e) a[0] += __bfloat162float(Y[(size_t)csr[e] * 64 + lane]);
    float acc = 0.f;
    #pragma unroll
    for (int t = 0; t < 32; ++t) acc += a[t];
    const int c = r1 - r0;
    const float sc = (c > 0) ? (1.0f / (float)c) : 1.0f;
    const float v = acc * sc + bl[lane] + __bfloat162float(R[(size_t)i * 64 + lane]);
    H[(size_t)i * 64 + lane] = fmaxf(v, 0.0f);
}

// ---- pooling: PP partial blocks per graph (sorted batch, binary search) -----
__global__ __launch_bounds__(256) void pool_part(const float* __restrict__ H,
                                                 const int* __restrict__ batch,
                                                 float* __restrict__ parts,
                                                 int* __restrict__ pcnt, int n) {
    const int b = blockIdx.x / PP;
    const int p = blockIdx.x % PP;
    int lo = 0, hi = n;
    while (lo < hi) { int m = (lo + hi) >> 1; if (batch[m] < b) lo = m + 1; else hi = m; }
    const int beg = lo;
    hi = n;
    while (lo < hi) { int m = (lo + hi) >> 1; if (batch[m] < b + 1) lo = m + 1; else hi = m; }
    const int end = lo;
    const int len = end - beg;
    const int chunk = (len + PP - 1) / PP;
    const int s0 = beg + p * chunk;
    int s1 = s0 + chunk; if (s1 > end) s1 = end;

    const int wid = threadIdx.x >> 6;
    const int lane = threadIdx.x & 63;
    float acc = 0.f;
    for (int i = s0 + wid; i < s1; i += 4)
        acc += H[(size_t)i * 64 + lane];
    __shared__ float part[4][64];
    part[wid][lane] = acc;
    __syncthreads();
    if (wid == 0) {
        const float s = (part[0][lane] + part[1][lane]) + (part[2][lane] + part[3][lane]);
        parts[(size_t)(b * PP + p) * 64 + lane] = s;
        if (lane == 0 && p == 0) pcnt[b] = len;
    }
}

// ---- final MLP: one block per graph, thread j owns output feature j ---------
__global__ __launch_bounds__(64) void final_mlp(const float* __restrict__ partsS,
                                                const int* __restrict__ cntS,
                                                const float* __restrict__ partsG,
                                                const int* __restrict__ cntG,
                                                const float* __restrict__ depth,
                                                const float* __restrict__ W1,
                                                const float* __restrict__ b1,
                                                const float* __restrict__ W2,
                                                const float* __restrict__ b2,
                                                float* __restrict__ out, int Bn) {
    const int b = blockIdx.x;
    const int j = threadIdx.x;  // 0..63
    float dsum = 0.f;
    for (int i = j; i < Bn; i += 64) dsum += depth[i];
    #pragma unroll
    for (int o = 32; o > 0; o >>= 1) dsum += __shfl_xor(dsum, o);
    const float mean = dsum / (float)Bn;
    float dvar = 0.f;
    for (int i = j; i < Bn; i += 64) { const float t = depth[i] - mean; dvar = fmaf(t, t, dvar); }
    #pragma unroll
    for (int o = 32; o > 0; o >>= 1) dvar += __shfl_xor(dvar, o);
    const float stdv = sqrtf(dvar / (float)Bn);
    const float dn = (depth[b] - mean) / (stdv + 1e-6f);

    __shared__ float f[129];
    {
        float s = 0.f, g = 0.f;
        #pragma unroll
        for (int p = 0; p < PP; ++p) {
            s += partsS[(size_t)(b * PP + p) * 64 + j];
            g += partsG[(size_t)(b * PP + p) * 64 + j];
        }
        int cs = cntS[b]; if (cs < 1) cs = 1;
        int cg = cntG[b]; if (cg < 1) cg = 1;
        f[j] = s / (float)cs;
        f[64 + j] = g / (float)cg;
        if (j == 0) f[128] = dn;
    }
    __syncthreads();
    float acc = b1[j];
    #pragma unroll 8
    for (int k = 0; k < 129; ++k)
        acc = fmaf(f[k], W1[(size_t)k * 64 + j], acc);
    float o = fmaxf(acc, 0.0f) * W2[j];
    #pragma unroll
    for (int of = 32; of > 0; of >>= 1) o += __shfl_xor(o, of);
    if (j == 0) out[b] = o + b2[0];
}

extern "C" void kernel_launch(void* const* d_in, const int* in_sizes, int n_in,
                              void* d_out, int out_size, void* d_ws, size_t ws_size,
                              hipStream_t stream) {
    const float* state_x     = (const float*)d_in[0];
    const int*   state_ei    = (const int*)d_in[1];
    const int*   state_batch = (const int*)d_in[2];
    const float* goal_x      = (const float*)d_in[3];
    const int*   goal_ei     = (const int*)d_in[4];
    const int*   goal_batch  = (const int*)d_in[5];
    const float* depth       = (const float*)d_in[6];
    const float* s1_Wl = (const float*)d_in[7];
    const float* s1_bl = (const float*)d_in[8];
    const float* s1_Wr = (const float*)d_in[9];
    const float* s2_Wl = (const float*)d_in[10];
    const float* s2_bl = (const float*)d_in[11];
    const float* s2_Wr = (const float*)d_in[12];
    const float* g1_Wl = (const float*)d_in[13];
    const float* g1_bl = (const float*)d_in[14];
    const float* g1_Wr = (const float*)d_in[15];
    const float* g2_Wl = (const float*)d_in[16];
    const float* g2_bl = (const float*)d_in[17];
    const float* g2_Wr = (const float*)d_in[18];
    const float* mlp_W1 = (const float*)d_in[19];
    const float* mlp_b1 = (const float*)d_in[20];
    const float* mlp_W2 = (const float*)d_in[21];
    const float* mlp_b2 = (const float*)d_in[22];

    const int N  = in_sizes[0] / 128;
    const int E  = in_sizes[1] / 2;
    const int Bn = in_sizes[6];
    const int nblk = (E + EPB - 1) / EPB;
    int bsh = 0;
    while (((size_t)NB << bsh) < (size_t)N) ++bsh;  // bucket width 2^bsh

    char* w = (char*)d_ws;
    auto alloc = [&](size_t bytes) {
        char* p = w;
        w += (bytes + 255) & ~(size_t)255;
        return p;
    };
    char*  bufYraw     = alloc((size_t)N * 64 * sizeof(float));  // bf16 Y + pairs alias
    char*  bufRraw     = alloc((size_t)N * 64 * sizeof(__hip_bfloat16));
    float* bufH        = (float*)alloc((size_t)N * 64 * sizeof(float));
    int*   csr         = (int*)alloc((size_t)2 * E * sizeof(int));
    int*   row_start   = (int*)alloc((size_t)2 * (N + 1) * sizeof(int));
    int*   blkhist     = (int*)alloc((size_t)2 * nblk * NB * sizeof(int));
    int*   basem       = (int*)alloc((size_t)2 * nblk * NB * sizeof(int));
    int*   bucket_base = (int*)alloc((size_t)2 * (NB + 1) * sizeof(int));
    float* partsS      = (float*)alloc((size_t)Bn * PP * 64 * sizeof(float));
    float* partsG      = (float*)alloc((size_t)Bn * PP * 64 * sizeof(float));
    int*   cntS        = (int*)alloc((size_t)Bn * sizeof(int));
    int*   cntG        = (int*)alloc((size_t)Bn * sizeof(int));
    __hip_bfloat16* bufY = (__hip_bfloat16*)bufYraw;
    __hip_bfloat16* bufR = (__hip_bfloat16*)bufRraw;
    int*   pairs       = (int*)bufYraw;  // packed pairs alias bufY (dead in CSR build)
    const size_t need = (size_t)(w - (char*)d_ws);
    const bool pairs_fit = (size_t)2 * E * sizeof(int) <= (size_t)N * 64 * sizeof(float);
    if (need > ws_size || (1 << bsh) > BWMAX || !pairs_fit || N > (1 << SRCB)) {
        hipMemsetAsync(d_out, 0, (size_t)out_size * sizeof(float), stream);
        return;
    }

    // ---- CSR build, both graphs ----
    p1_hist<<<2 * nblk, 256, 0, stream>>>(state_ei + E, goal_ei + E, blkhist, E, bsh, nblk);
    p1_scan<<<2, NB, 0, stream>>>(blkhist, basem, bucket_base, nblk);
    p1_scatter<<<2 * nblk, 256, 0, stream>>>(state_ei, goal_ei, basem, pairs, E, bsh, nblk);
    p2_sort<<<2 * NB, 512, 0, stream>>>(pairs, bucket_base, csr, row_start, N, E, bsh);

    const int g64 = (N + 63) / 64;
    const int g4  = (N + 3) / 4;
    const int* csrS = csr;
    const int* csrG = csr + E;
    const int* rsS  = row_start;
    const int* rsG  = row_start + (N + 1);

    // ---- state encoder ----
    gemm_fused<128><<<g64, 512, 0, stream>>>(state_x, s1_Wl, s1_Wr, bufY, bufR, N);
    agg_fused<<<g4, 256, 0, stream>>>(bufY, bufR, s1_bl, csrS, rsS, bufH, N);
    gemm_fused<64><<<g64, 512, 0, stream>>>(bufH, s2_Wl, s2_Wr, bufY, bufR, N);
    agg_fused<<<g4, 256, 0, stream>>>(bufY, bufR, s2_bl, csrS, rsS, bufH, N);
    pool_part<<<Bn * PP, 256, 0, stream>>>(bufH, state_batch, partsS, cntS, N);

    // ---- goal encoder ----
    gemm_fused<128><<<g64, 512, 0, stream>>>(goal_x, g1_Wl, g1_Wr, bufY, bufR, N);
    agg_fused<<<g4, 256, 0, stream>>>(bufY, bufR, g1_bl, csrG, rsG, bufH, N);
    gemm_fused<64><<<g64, 512, 0, stream>>>(bufH, g2_Wl, g2_Wr, bufY, bufR, N);
    agg_fused<<<g4, 256, 0, stream>>>(bufY, bufR, g2_bl, csrG, rsG, bufH, N);
    pool_part<<<Bn * PP, 256, 0, stream>>>(bufH, goal_batch, partsG, cntG, N);

    final_mlp<<<Bn, 64, 0, stream>>>(partsS, cntS, partsG, cntG, depth,
                                     mlp_W1, mlp_b1, mlp_W2, mlp_b2, (float*)d_out, Bn);
}

// Round 17
// 578.178 us; speedup vs baseline: 1.1533x; 1.1078x over previous
//
#include <hip/hip_runtime.h>
#include <hip/hip_bf16.h>
#include <hip/hip_fp16.h>

// ---------------------------------------------------------------------------
// GraphSAGE distance estimator.
//   CSR build (both graphs batched): LDS bucket hist -> scan -> bucket-grouped
//   scatter of PACKED (src | dlocal<<17) ints -> per-bucket LDS counting sort
//   with LDS staging (contiguous flush) + parallel block scan.
//   Per layer: {Y,R} = x@{Wl,Wr} fused GEMM with f16 operands in LDS and
//   v_dot2_f32_f16 (2 MAC/instr, fp32 accum): halves BOTH the VALU and the
//   LDS instruction streams (R16: the two pipes were balanced at ~60% each,
//   10 ds_read ~120cy vs 64 fmaf ~128cy per k4). 24KB LDS -> 4 blocks/CU.
//   Y,R stored BF16 (agg gather row = one line); f16 GEMM input rounding is
//   sub-dominant to that storage error. fp32 accumulation everywhere.
//   H = relu(csr-mean(Y) + bl + R) fused into aggregate; agg 32-deep unroll.
//   Pool: 8 partial blocks -> final_mlp (block/graph, thread j owns feature j).
// ---------------------------------------------------------------------------

#define NB    128    // dst buckets (pow2)
#define EPB   16384  // edges per grouping block
#define BWMAX 1024   // max nodes per bucket (LDS arrays in sort)
#define PP    8      // pool partials per graph
#define SRCB  17     // bits for src id in packed pair (N <= 131072)
#define SCAP  28672  // staged edges per bucket (112 KB LDS)

typedef _Float16 v2h __attribute__((ext_vector_type(2)));
union U2H { unsigned int u; v2h h; __half2 hh; };

static __device__ __forceinline__ unsigned int pack2(float a, float b) {
    U2H t; t.hh = __floats2half2_rn(a, b); return t.u;
}
static __device__ __forceinline__ float dot2(unsigned int x, unsigned int w, float acc) {
    U2H xa, wa; xa.u = x; wa.u = w;
    return __builtin_amdgcn_fdot2(xa.h, wa.h, acc, false);
}

// ---- CSR build (batched over both graphs) ----------------------------------

__global__ __launch_bounds__(256) void p1_hist(const int* __restrict__ dstS,
                                               const int* __restrict__ dstG,
                                               int* __restrict__ blkhist,
                                               int E, int bsh, int nblk) {
    const int g = blockIdx.x / nblk;
    const int blk = blockIdx.x % nblk;
    const int* __restrict__ dst = g ? dstG : dstS;
    __shared__ int h[NB];
    for (int i = threadIdx.x; i < NB; i += 256) h[i] = 0;
    __syncthreads();
    const int base = blk * EPB;
    for (int k = 0; k < EPB; k += 256) {
        const int e = base + k + threadIdx.x;
        if (e < E) atomicAdd(&h[dst[e] >> bsh], 1);
    }
    __syncthreads();
    for (int i = threadIdx.x; i < NB; i += 256)
        blkhist[((size_t)(g * nblk + blk)) * NB + i] = h[i];
}

__global__ __launch_bounds__(NB) void p1_scan(const int* __restrict__ blkhist,
                                              int* __restrict__ basem,
                                              int* __restrict__ bucket_base,
                                              int nblk) {
    __shared__ int lds[NB];
    const int g = blockIdx.x;
    const int* __restrict__ bh = blkhist + (size_t)g * nblk * NB;
    int* __restrict__ bm = basem + (size_t)g * nblk * NB;
    int* __restrict__ bb = bucket_base + (size_t)g * (NB + 1);
    const int b = threadIdx.x;
    int s = 0;
    int k = 0;
    for (; k + 8 <= nblk; k += 8) {
        int v[8];
        #pragma unroll
        for (int t = 0; t < 8; ++t) v[t] = bh[(size_t)(k + t) * NB + b];
        #pragma unroll
        for (int t = 0; t < 8; ++t) s += v[t];
    }
    for (; k < nblk; ++k) s += bh[(size_t)k * NB + b];
    lds[b] = s;
    __syncthreads();
    for (int off = 1; off < NB; off <<= 1) {
        int v = (b >= off) ? lds[b - off] : 0;
        __syncthreads();
        lds[b] += v;
        __syncthreads();
    }
    int run = lds[b] - s;  // exclusive prefix
    bb[b] = run;
    if (b == NB - 1) bb[NB] = run + s;
    k = 0;
    for (; k + 8 <= nblk; k += 8) {
        int c[8];
        #pragma unroll
        for (int t = 0; t < 8; ++t) c[t] = bh[(size_t)(k + t) * NB + b];
        #pragma unroll
        for (int t = 0; t < 8; ++t) {
            bm[(size_t)(k + t) * NB + b] = run;
            run += c[t];
        }
    }
    for (; k < nblk; ++k) {
        const int c = bh[(size_t)k * NB + b];
        bm[(size_t)k * NB + b] = run;
        run += c;
    }
}

__global__ __launch_bounds__(256) void p1_scatter(const int* __restrict__ eiS,
                                                  const int* __restrict__ eiG,
                                                  const int* __restrict__ basem,
                                                  int* __restrict__ pairs,
                                                  int E, int bsh, int nblk) {
    const int g = blockIdx.x / nblk;
    const int blk = blockIdx.x % nblk;
    const int* __restrict__ src = g ? eiG : eiS;
    const int* __restrict__ dst = src + E;
    int* __restrict__ pr = pairs + (size_t)g * E;
    const int bwm = (1 << bsh) - 1;
    __shared__ int cur[NB];
    for (int i = threadIdx.x; i < NB; i += 256)
        cur[i] = basem[((size_t)(g * nblk + blk)) * NB + i];
    __syncthreads();
    const int base = blk * EPB;
    for (int k = 0; k < EPB; k += 256) {
        const int e = base + k + threadIdx.x;
        if (e < E) {
            const int d = dst[e];
            const int s = src[e];
            const int p = atomicAdd(&cur[d >> bsh], 1);
            pr[p] = s | ((d & bwm) << SRCB);   // packed: src(17b) | dlocal(<=10b)
        }
    }
}

// Per-bucket counting sort with LDS staging + parallel block scan.
__global__ __launch_bounds__(512) void p2_sort(const int* __restrict__ pairs,
                                               const int* __restrict__ bucket_base,
                                               int* __restrict__ csr,
                                               int* __restrict__ row_start,
                                               int N, int E, int bsh) {
    __shared__ int stage[SCAP];   // 112 KB
    __shared__ int cnt[BWMAX];    // 4 KB
    __shared__ int off[BWMAX];    // 4 KB
    __shared__ int ws[512];       // 2 KB
    const int g = blockIdx.x / NB;
    const int b = blockIdx.x % NB;
    const int bw = 1 << bsh;
    const int lo = b * bw;
    int nn = N - lo;
    if (nn <= 0) return;
    if (nn > bw) nn = bw;
    const int* __restrict__ pr = pairs + (size_t)g * E;
    const int* __restrict__ bb = bucket_base + (size_t)g * (NB + 1);
    int* __restrict__ cs = csr + (size_t)g * E;
    int* __restrict__ rs = row_start + (size_t)g * (N + 1);
    const int tid = threadIdx.x;
    for (int i = tid; i < nn; i += 512) cnt[i] = 0;
    __syncthreads();
    const int e0 = bb[b];
    const int e1 = bb[b + 1];
    const int ne = e1 - e0;
    for (int e = e0 + tid; e < e1; e += 512)
        atomicAdd(&cnt[pr[e] >> SRCB], 1);
    __syncthreads();
    {
        const int i0 = 2 * tid, i1 = 2 * tid + 1;
        const int c0 = (i0 < nn) ? cnt[i0] : 0;
        const int c1 = (i1 < nn) ? cnt[i1] : 0;
        const int s = c0 + c1;
        ws[tid] = s;
        __syncthreads();
        for (int o = 1; o < 512; o <<= 1) {
            int v = (tid >= o) ? ws[tid - o] : 0;
            __syncthreads();
            ws[tid] += v;
            __syncthreads();
        }
        const int base = e0 + ws[tid] - s;  // exclusive
        if (i0 < nn) off[i0] = base;
        if (i1 < nn) off[i1] = base + c0;
    }
    __syncthreads();
    for (int i = tid; i < nn; i += 512) {
        rs[lo + i] = off[i];
        cnt[i] = off[i];  // reuse as cursor
    }
    if (lo + nn == N && tid == 0) rs[N] = e1;
    __syncthreads();
    if (ne <= SCAP) {
        for (int e = e0 + tid; e < e1; e += 512) {
            const int v = pr[e];
            const int pos = atomicAdd(&cnt[v >> SRCB], 1);
            stage[pos - e0] = v & ((1 << SRCB) - 1);
        }
        __syncthreads();
        for (int i = tid; i < ne; i += 512) cs[e0 + i] = stage[i];
    } else {
        for (int e = e0 + tid; e < e1; e += 512) {
            const int v = pr[e];
            const int pos = atomicAdd(&cnt[v >> SRCB], 1);
            cs[pos] = v & ((1 << SRCB) - 1);
        }
    }
}

// ---- fused dual-weight GEMM: Y(bf16) = x@Wl, R(bf16) = x@Wr -----------------
// 512 thr = 8 waves x 8 rows = 64 rows/block, KC=64 chunks. f16 operands:
// ldsW quads (wl2,wr2,wl2',wr2') per 4-k group (16KB), x rows as f16 pairs
// (8KB). Inner loop per 8-k: 2 W b128 + 8 x b128 reads, 64 v_dot2_f32_f16.
template <int K>
__global__ __launch_bounds__(512) void gemm_fused(const float* __restrict__ x,
                                                  const float* __restrict__ Wl,
                                                  const float* __restrict__ Wr,
                                                  __hip_bfloat16* __restrict__ Y,
                                                  __hip_bfloat16* __restrict__ R, int n) {
    constexpr int KC = 64;
    constexpr int ROWS = 64;
    __shared__ uint4 ldsW4[(KC / 4) * 64];          // 16 KB
    __shared__ unsigned int ldsXu[ROWS * (KC / 2)]; // 8 KB
    const int tid = threadIdx.x;
    const int lane = tid & 63;
    const int wid = tid >> 6;
    const int rbase = blockIdx.x * ROWS;

    float accY[8], accR[8];
    #pragma unroll
    for (int r = 0; r < 8; ++r) { accY[r] = 0.f; accR[r] = 0.f; }

    for (int k0 = 0; k0 < K; k0 += KC) {
        __syncthreads();
        // stage W: quad per (4-k group gp, col c): (wl(k,k+1), wr(k,k+1), wl(k+2,k+3), wr(k+2,k+3))
        for (int i = tid; i < (KC / 4) * 64; i += 512) {
            const int gp = i >> 6;
            const int c = i & 63;
            const int ka = k0 + gp * 4;
            const float wl0 = Wl[(size_t)ka * 64 + c],       wr0 = Wr[(size_t)ka * 64 + c];
            const float wl1 = Wl[(size_t)(ka + 1) * 64 + c], wr1 = Wr[(size_t)(ka + 1) * 64 + c];
            const float wl2 = Wl[(size_t)(ka + 2) * 64 + c], wr2 = Wr[(size_t)(ka + 2) * 64 + c];
            const float wl3 = Wl[(size_t)(ka + 3) * 64 + c], wr3 = Wr[(size_t)(ka + 3) * 64 + c];
            ldsW4[i] = make_uint4(pack2(wl0, wl1), pack2(wr0, wr1),
                                  pack2(wl2, wl3), pack2(wr2, wr3));
        }
        // stage x tile as f16 pairs
        {
            constexpr int F4R = KC / 4;  // float4 per row = 16
            for (int i = tid; i < ROWS * F4R; i += 512) {
                const int rr = i / F4R;
                const int cc = i % F4R;
                int row = rbase + rr;
                if (row > n - 1) row = n - 1;
                const float4 xv = *(const float4*)(x + (size_t)row * K + k0 + cc * 4);
                ldsXu[rr * (KC / 2) + cc * 2 + 0] = pack2(xv.x, xv.y);
                ldsXu[rr * (KC / 2) + cc * 2 + 1] = pack2(xv.z, xv.w);
            }
        }
        __syncthreads();
        const int rw = wid * 8;
        #pragma unroll 2
        for (int k8 = 0; k8 < KC / 8; ++k8) {
            const uint4 w0 = ldsW4[(k8 * 2 + 0) * 64 + lane]; // k..k+3
            const uint4 w1 = ldsW4[(k8 * 2 + 1) * 64 + lane]; // k+4..k+7
            #pragma unroll
            for (int r = 0; r < 8; ++r) {
                const uint4 xq = *(const uint4*)(&ldsXu[(rw + r) * (KC / 2) + k8 * 4]);
                float yv = accY[r];
                float zv = accR[r];
                yv = dot2(xq.x, w0.x, yv);
                zv = dot2(xq.x, w0.y, zv);
                yv = dot2(xq.y, w0.z, yv);
                zv = dot2(xq.y, w0.w, zv);
                yv = dot2(xq.z, w1.x, yv);
                zv = dot2(xq.z, w1.y, zv);
                yv = dot2(xq.w, w1.z, yv);
                zv = dot2(xq.w, w1.w, zv);
                accY[r] = yv;
                accR[r] = zv;
            }
        }
    }
    #pragma unroll
    for (int r = 0; r < 8; ++r) {
        const int row = rbase + wid * 8 + r;
        if (row < n) {
            Y[(size_t)row * 64 + lane] = __float2bfloat16(accY[r]);
            R[(size_t)row * 64 + lane] = __float2bfloat16(accR[r]);
        }
    }
}

// ---- aggregate + epilogue: H = relu(mean_csr(Y) + bl + R) -------------------
__global__ __launch_bounds__(256) void agg_fused(const __hip_bfloat16* __restrict__ Y,
                                                 const __hip_bfloat16* __restrict__ R,
                                                 const float* __restrict__ bl,
                                                 const int* __restrict__ csr,
                                                 const int* __restrict__ row_start,
                                                 float* __restrict__ H, int n) {
    const int wid = threadIdx.x >> 6;
    const int lane = threadIdx.x & 63;
    const int i = blockIdx.x * 4 + wid;
    if (i >= n) return;
    const int r0 = __builtin_amdgcn_readfirstlane(row_start[i]);
    const int r1 = __builtin_amdgcn_readfirstlane(row_start[i + 1]);
    float a[32];
    #pragma unroll
    for (int t = 0; t < 32; ++t) a[t] = 0.f;
    int e = r0;
    for (; e + 32 <= r1; e += 32) {
        #pragma unroll
        for (int t = 0; t < 32; ++t)
            a[t] += __bfloat162float(Y[(size_t)csr[e + t] * 64 + lane]);
    }
    for (; e + 8 <= r1; e += 8) {
        #pragma unroll
        for (int t = 0; t < 8; ++t)
            a[t] += __bfloat162float(Y[(size_t)csr[e + t] * 64 + lane]);
    }
    for (; e < r1; ++e) a[0] += __bfloat162float(Y[(size_t)csr[e] * 64 + lane]);
    float acc = 0.f;
    #pragma unroll
    for (int t = 0; t < 32; ++t) acc += a[t];
    const int c = r1 - r0;
    const float sc = (c > 0) ? (1.0f / (float)c) : 1.0f;
    const float v = acc * sc + bl[lane] + __bfloat162float(R[(size_t)i * 64 + lane]);
    H[(size_t)i * 64 + lane] = fmaxf(v, 0.0f);
}

// ---- pooling: PP partial blocks per graph (sorted batch, binary search) -----
__global__ __launch_bounds__(256) void pool_part(const float* __restrict__ H,
                                                 const int* __restrict__ batch,
                                                 float* __restrict__ parts,
                                                 int* __restrict__ pcnt, int n) {
    const int b = blockIdx.x / PP;
    const int p = blockIdx.x % PP;
    int lo = 0, hi = n;
    while (lo < hi) { int m = (lo + hi) >> 1; if (batch[m] < b) lo = m + 1; else hi = m; }
    const int beg = lo;
    hi = n;
    while (lo < hi) { int m = (lo + hi) >> 1; if (batch[m] < b + 1) lo = m + 1; else hi = m; }
    const int end = lo;
    const int len = end - beg;
    const int chunk = (len + PP - 1) / PP;
    const int s0 = beg + p * chunk;
    int s1 = s0 + chunk; if (s1 > end) s1 = end;

    const int wid = threadIdx.x >> 6;
    const int lane = threadIdx.x & 63;
    float acc = 0.f;
    for (int i = s0 + wid; i < s1; i += 4)
        acc += H[(size_t)i * 64 + lane];
    __shared__ float part[4][64];
    part[wid][lane] = acc;
    __syncthreads();
    if (wid == 0) {
        const float s = (part[0][lane] + part[1][lane]) + (part[2][lane] + part[3][lane]);
        parts[(size_t)(b * PP + p) * 64 + lane] = s;
        if (lane == 0 && p == 0) pcnt[b] = len;
    }
}

// ---- final MLP: one block per graph, thread j owns output feature j ---------
__global__ __launch_bounds__(64) void final_mlp(const float* __restrict__ partsS,
                                                const int* __restrict__ cntS,
                                                const float* __restrict__ partsG,
                                                const int* __restrict__ cntG,
                                                const float* __restrict__ depth,
                                                const float* __restrict__ W1,
                                                const float* __restrict__ b1,
                                                const float* __restrict__ W2,
                                                const float* __restrict__ b2,
                                                float* __restrict__ out, int Bn) {
    const int b = blockIdx.x;
    const int j = threadIdx.x;  // 0..63
    float dsum = 0.f;
    for (int i = j; i < Bn; i += 64) dsum += depth[i];
    #pragma unroll
    for (int o = 32; o > 0; o >>= 1) dsum += __shfl_xor(dsum, o);
    const float mean = dsum / (float)Bn;
    float dvar = 0.f;
    for (int i = j; i < Bn; i += 64) { const float t = depth[i] - mean; dvar = fmaf(t, t, dvar); }
    #pragma unroll
    for (int o = 32; o > 0; o >>= 1) dvar += __shfl_xor(dvar, o);
    const float stdv = sqrtf(dvar / (float)Bn);
    const float dn = (depth[b] - mean) / (stdv + 1e-6f);

    __shared__ float f[129];
    {
        float s = 0.f, g = 0.f;
        #pragma unroll
        for (int p = 0; p < PP; ++p) {
            s += partsS[(size_t)(b * PP + p) * 64 + j];
            g += partsG[(size_t)(b * PP + p) * 64 + j];
        }
        int cs = cntS[b]; if (cs < 1) cs = 1;
        int cg = cntG[b]; if (cg < 1) cg = 1;
        f[j] = s / (float)cs;
        f[64 + j] = g / (float)cg;
        if (j == 0) f[128] = dn;
    }
    __syncthreads();
    float acc = b1[j];
    #pragma unroll 8
    for (int k = 0; k < 129; ++k)
        acc = fmaf(f[k], W1[(size_t)k * 64 + j], acc);
    float o = fmaxf(acc, 0.0f) * W2[j];
    #pragma unroll
    for (int of = 32; of > 0; of >>= 1) o += __shfl_xor(o, of);
    if (j == 0) out[b] = o + b2[0];
}

extern "C" void kernel_launch(void* const* d_in, const int* in_sizes, int n_in,
                              void* d_out, int out_size, void* d_ws, size_t ws_size,
                              hipStream_t stream) {
    const float* state_x     = (const float*)d_in[0];
    const int*   state_ei    = (const int*)d_in[1];
    const int*   state_batch = (const int*)d_in[2];
    const float* goal_x      = (const float*)d_in[3];
    const int*   goal_ei     = (const int*)d_in[4];
    const int*   goal_batch  = (const int*)d_in[5];
    const float* depth       = (const float*)d_in[6];
    const float* s1_Wl = (const float*)d_in[7];
    const float* s1_bl = (const float*)d_in[8];
    const float* s1_Wr = (const float*)d_in[9];
    const float* s2_Wl = (const float*)d_in[10];
    const float* s2_bl = (const float*)d_in[11];
    const float* s2_Wr = (const float*)d_in[12];
    const float* g1_Wl = (const float*)d_in[13];
    const float* g1_bl = (const float*)d_in[14];
    const float* g1_Wr = (const float*)d_in[15];
    const float* g2_Wl = (const float*)d_in[16];
    const float* g2_bl = (const float*)d_in[17];
    const float* g2_Wr = (const float*)d_in[18];
    const float* mlp_W1 = (const float*)d_in[19];
    const float* mlp_b1 = (const float*)d_in[20];
    const float* mlp_W2 = (const float*)d_in[21];
    const float* mlp_b2 = (const float*)d_in[22];

    const int N  = in_sizes[0] / 128;
    const int E  = in_sizes[1] / 2;
    const int Bn = in_sizes[6];
    const int nblk = (E + EPB - 1) / EPB;
    int bsh = 0;
    while (((size_t)NB << bsh) < (size_t)N) ++bsh;  // bucket width 2^bsh

    char* w = (char*)d_ws;
    auto alloc = [&](size_t bytes) {
        char* p = w;
        w += (bytes + 255) & ~(size_t)255;
        return p;
    };
    char*  bufYraw     = alloc((size_t)N * 64 * sizeof(float));  // bf16 Y + pairs alias
    char*  bufRraw     = alloc((size_t)N * 64 * sizeof(__hip_bfloat16));
    float* bufH        = (float*)alloc((size_t)N * 64 * sizeof(float));
    int*   csr         = (int*)alloc((size_t)2 * E * sizeof(int));
    int*   row_start   = (int*)alloc((size_t)2 * (N + 1) * sizeof(int));
    int*   blkhist     = (int*)alloc((size_t)2 * nblk * NB * sizeof(int));
    int*   basem       = (int*)alloc((size_t)2 * nblk * NB * sizeof(int));
    int*   bucket_base = (int*)alloc((size_t)2 * (NB + 1) * sizeof(int));
    float* partsS      = (float*)alloc((size_t)Bn * PP * 64 * sizeof(float));
    float* partsG      = (float*)alloc((size_t)Bn * PP * 64 * sizeof(float));
    int*   cntS        = (int*)alloc((size_t)Bn * sizeof(int));
    int*   cntG        = (int*)alloc((size_t)Bn * sizeof(int));
    __hip_bfloat16* bufY = (__hip_bfloat16*)bufYraw;
    __hip_bfloat16* bufR = (__hip_bfloat16*)bufRraw;
    int*   pairs       = (int*)bufYraw;  // packed pairs alias bufY (dead in CSR build)
    const size_t need = (size_t)(w - (char*)d_ws);
    const bool pairs_fit = (size_t)2 * E * sizeof(int) <= (size_t)N * 64 * sizeof(float);
    if (need > ws_size || (1 << bsh) > BWMAX || !pairs_fit || N > (1 << SRCB)) {
        hipMemsetAsync(d_out, 0, (size_t)out_size * sizeof(float), stream);
        return;
    }

    // ---- CSR build, both graphs ----
    p1_hist<<<2 * nblk, 256, 0, stream>>>(state_ei + E, goal_ei + E, blkhist, E, bsh, nblk);
    p1_scan<<<2, NB, 0, stream>>>(blkhist, basem, bucket_base, nblk);
    p1_scatter<<<2 * nblk, 256, 0, stream>>>(state_ei, goal_ei, basem, pairs, E, bsh, nblk);
    p2_sort<<<2 * NB, 512, 0, stream>>>(pairs, bucket_base, csr, row_start, N, E, bsh);

    const int g64 = (N + 63) / 64;
    const int g4  = (N + 3) / 4;
    const int* csrS = csr;
    const int* csrG = csr + E;
    const int* rsS  = row_start;
    const int* rsG  = row_start + (N + 1);

    // ---- state encoder ----
    gemm_fused<128><<<g64, 512, 0, stream>>>(state_x, s1_Wl, s1_Wr, bufY, bufR, N);
    agg_fused<<<g4, 256, 0, stream>>>(bufY, bufR, s1_bl, csrS, rsS, bufH, N);
    gemm_fused<64><<<g64, 512, 0, stream>>>(bufH, s2_Wl, s2_Wr, bufY, bufR, N);
    agg_fused<<<g4, 256, 0, stream>>>(bufY, bufR, s2_bl, csrS, rsS, bufH, N);
    pool_part<<<Bn * PP, 256, 0, stream>>>(bufH, state_batch, partsS, cntS, N);

    // ---- goal encoder ----
    gemm_fused<128><<<g64, 512, 0, stream>>>(goal_x, g1_Wl, g1_Wr, bufY, bufR, N);
    agg_fused<<<g4, 256, 0, stream>>>(bufY, bufR, g1_bl, csrG, rsG, bufH, N);
    gemm_fused<64><<<g64, 512, 0, stream>>>(bufH, g2_Wl, g2_Wr, bufY, bufR, N);
    agg_fused<<<g4, 256, 0, stream>>>(bufY, bufR, g2_bl, csrG, rsG, bufH, N);
    pool_part<<<Bn * PP, 256, 0, stream>>>(bufH, goal_batch, partsG, cntG, N);

    final_mlp<<<Bn, 64, 0, stream>>>(partsS, cntS, partsG, cntG, depth,
                                     mlp_W1, mlp_b1, mlp_W2, mlp_b2, (float*)d_out, Bn);
}